// Round 1
// baseline (424.321 us; speedup 1.0000x reference)
//
#include <hip/hip_runtime.h>
#include <stdint.h>

#define M_ROWS 65536
#define C_DIM  256
#define K_CLS  20
#define P_POS  2048
#define MARGIN_F 0.3f
#define EPS_D (0.0001f / 256.0f)

typedef short  short8  __attribute__((ext_vector_type(8)));
typedef float  floatx4 __attribute__((ext_vector_type(4)));

__device__ __forceinline__ unsigned short f2bf(float x) {
    uint32_t u = __float_as_uint(x);
    u += 0x7fffu + ((u >> 16) & 1u);   // RNE
    return (unsigned short)(u >> 16);
}
__device__ __forceinline__ float bf2f(unsigned short h) {
    return __uint_as_float(((uint32_t)h) << 16);
}

// ---------------- Kernel 1: sigmoid -> bf16 store + fp32 row norms ----------
__global__ __launch_bounds__(256) void sigmoid_norm_k(
        const float* __restrict__ feat,
        unsigned short* __restrict__ Sb,
        float* __restrict__ xx) {
    const int wave = threadIdx.x >> 6, lane = threadIdx.x & 63;
    const int row = blockIdx.x * 4 + wave;
    const float4 v = *(const float4*)(feat + (size_t)row * C_DIM + lane * 4);

    unsigned short b0 = f2bf(1.f / (1.f + __expf(-v.x)));
    unsigned short b1 = f2bf(1.f / (1.f + __expf(-v.y)));
    unsigned short b2 = f2bf(1.f / (1.f + __expf(-v.z)));
    unsigned short b3 = f2bf(1.f / (1.f + __expf(-v.w)));

    ushort4 st; st.x = b0; st.y = b1; st.z = b2; st.w = b3;
    *(ushort4*)(Sb + (size_t)row * C_DIM + lane * 4) = st;

    // norm from the bf16-rounded values (consistency with MFMA inputs)
    float s0 = bf2f(b0), s1 = bf2f(b1), s2 = bf2f(b2), s3 = bf2f(b3);
    float sum = s0 * s0 + s1 * s1 + s2 * s2 + s3 * s3;
#pragma unroll
    for (int off = 32; off; off >>= 1) sum += __shfl_down(sum, off);
    if (lane == 0) xx[row] = sum;
}

// ---------------- Kernel 2: fused distance-GEMM + arg-select ----------------
// grid: (32 i-tiles, 2 types, 20 classes), block 256 (4 waves)
// type 0: B=pos, argmax -> hp ; type 1: B=neg, argmin -> hn
#define LDPAD 264   // 256 + 8 bf16 pad (16B) -> 2-way LDS conflicts only
__global__ __launch_bounds__(256) void select_k(
        const unsigned short* __restrict__ Sb,
        const float* __restrict__ xx,
        const int* __restrict__ pos_idx,
        const int* __restrict__ neg_idx,
        int* __restrict__ hp,
        int* __restrict__ hn) {
    __shared__ __align__(16) unsigned short At[64 * LDPAD];
    __shared__ __align__(16) unsigned short Bt[64 * LDPAD];
    __shared__ float xxA[64];
    __shared__ float yyB[64];

    const int tid    = threadIdx.x;
    const int wave   = tid >> 6;
    const int lane   = tid & 63;
    const int lane15 = lane & 15;
    const int quad   = lane >> 4;
    const int k      = blockIdx.z;
    const int isNeg  = blockIdx.y;
    const int i0     = blockIdx.x * 64;

    const int* idxA   = pos_idx + k * P_POS;
    const int* idxB   = (isNeg ? neg_idx : pos_idx) + k * P_POS;
    int*       outIdx = (isNeg ? hn : hp) + k * P_POS;

    // ---- stage A tile (64 rows x 256 cols) ----
#pragma unroll
    for (int it = 0; it < 8; ++it) {
        int c = it * 256 + tid;
        int row = c >> 5, cc = c & 31;
        int g = idxA[i0 + row];
        *(uint4*)(&At[row * LDPAD + cc * 8]) =
            *(const uint4*)(Sb + (size_t)g * C_DIM + cc * 8);
    }
    if (tid < 64) xxA[tid] = xx[idxA[i0 + tid]];

    float bestv[4];
    int   bestj[4];
    const float binit = isNeg ? 3.4e38f : -1.0f;
#pragma unroll
    for (int r = 0; r < 4; ++r) { bestv[r] = binit; bestj[r] = 0; }

    for (int jc = 0; jc < 32; ++jc) {
        const int j0 = jc * 64;
        __syncthreads();   // protect Bt/yyB from previous iteration's readers
#pragma unroll
        for (int it = 0; it < 8; ++it) {
            int c = it * 256 + tid;
            int row = c >> 5, cc = c & 31;
            int g = idxB[j0 + row];
            *(uint4*)(&Bt[row * LDPAD + cc * 8]) =
                *(const uint4*)(Sb + (size_t)g * C_DIM + cc * 8);
        }
        if (tid < 64) yyB[tid] = xx[idxB[j0 + tid]];
        __syncthreads();

        floatx4 acc[4];
#pragma unroll
        for (int ct = 0; ct < 4; ++ct) acc[ct] = (floatx4){0.f, 0.f, 0.f, 0.f};
#pragma unroll
        for (int k0 = 0; k0 < 256; k0 += 32) {
            short8 af = *(const short8*)(&At[(wave * 16 + lane15) * LDPAD + k0 + quad * 8]);
#pragma unroll
            for (int ct = 0; ct < 4; ++ct) {
                short8 bf = *(const short8*)(&Bt[(ct * 16 + lane15) * LDPAD + k0 + quad * 8]);
                acc[ct] = __builtin_amdgcn_mfma_f32_16x16x32_bf16(af, bf, acc[ct], 0, 0, 0);
            }
        }

        // epilogue: score = clamp(xx_i - 2*D + yy_j, 0); running arg-select
#pragma unroll
        for (int ct = 0; ct < 4; ++ct) {
            const float yv = yyB[ct * 16 + lane15];
            const int j = j0 + ct * 16 + lane15;
#pragma unroll
            for (int r = 0; r < 4; ++r) {
                const float xv = xxA[wave * 16 + quad * 4 + r];
                const float v = fmaxf(xv - 2.0f * acc[ct][r] + yv, 0.0f);
                bool better = isNeg
                    ? (v < bestv[r] || (v == bestv[r] && j < bestj[r]))
                    : (v > bestv[r] || (v == bestv[r] && j < bestj[r]));
                if (better) { bestv[r] = v; bestj[r] = j; }
            }
        }
    }

    // cross-lane reduce within the 16-lane quad group (first-index tie-break)
#pragma unroll
    for (int r = 0; r < 4; ++r) {
#pragma unroll
        for (int off = 1; off < 16; off <<= 1) {
            float ov = __shfl_xor(bestv[r], off);
            int   oj = __shfl_xor(bestj[r], off);
            bool better = isNeg
                ? (ov < bestv[r] || (ov == bestv[r] && oj < bestj[r]))
                : (ov > bestv[r] || (ov == bestv[r] && oj < bestj[r]));
            if (better) { bestv[r] = ov; bestj[r] = oj; }
        }
    }
    if (lane15 == 0) {
#pragma unroll
        for (int r = 0; r < 4; ++r)
            outIdx[i0 + wave * 16 + quad * 4 + r] = bestj[r];
    }
}

// ---------------- Kernel 3: per-anchor fp32 pdist + triplet term ------------
__global__ __launch_bounds__(256) void loss_k(
        const unsigned short* __restrict__ Sb,
        const int* __restrict__ pos_idx,
        const int* __restrict__ neg_idx,
        const int* __restrict__ hp,
        const int* __restrict__ hn,
        float* __restrict__ terms) {
    const int wave = threadIdx.x >> 6, lane = threadIdx.x & 63;
    const int a = blockIdx.x * 4 + wave;
    const int k = a >> 11;
    const int i = a & 2047;
    const int* pidx = pos_idx + (k << 11);
    const int* nidx = neg_idx + (k << 11);
    const int ga = pidx[i];
    const int gp = pidx[hp[a]];
    const int gn = nidx[hn[a]];

    const ushort4 va = *(const ushort4*)(Sb + (size_t)ga * C_DIM + lane * 4);
    const ushort4 vp = *(const ushort4*)(Sb + (size_t)gp * C_DIM + lane * 4);
    const ushort4 vn = *(const ushort4*)(Sb + (size_t)gn * C_DIM + lane * 4);

    float dp = 0.f, dn = 0.f;
    {
        float xa, d;
        xa = bf2f(va.x); d = xa - bf2f(vp.x); dp += d * d; d = xa - bf2f(vn.x); dn += d * d;
        xa = bf2f(va.y); d = xa - bf2f(vp.y); dp += d * d; d = xa - bf2f(vn.y); dn += d * d;
        xa = bf2f(va.z); d = xa - bf2f(vp.z); dp += d * d; d = xa - bf2f(vn.z); dn += d * d;
        xa = bf2f(va.w); d = xa - bf2f(vp.w); dp += d * d; d = xa - bf2f(vn.w); dn += d * d;
    }
#pragma unroll
    for (int off = 32; off; off >>= 1) {
        dp += __shfl_down(dp, off);
        dn += __shfl_down(dn, off);
    }
    if (lane == 0) {
        float d_p = sqrtf(fmaxf(dp, 0.f) + EPS_D);
        float d_n = sqrtf(fmaxf(dn, 0.f) + EPS_D);
        terms[a] = fmaxf(MARGIN_F + d_p - d_n, 0.f);
    }
}

// ---------------- Kernel 4: final reduction (sum of class means) ------------
__global__ __launch_bounds__(1024) void reduce_k(
        const float* __restrict__ terms, float* __restrict__ out) {
    __shared__ float red[1024];
    float s = 0.f;
    for (int i = threadIdx.x; i < K_CLS * P_POS; i += 1024) s += terms[i];
    red[threadIdx.x] = s;
    __syncthreads();
    for (int off = 512; off; off >>= 1) {
        if ((int)threadIdx.x < off) red[threadIdx.x] += red[threadIdx.x + off];
        __syncthreads();
    }
    if (threadIdx.x == 0) out[0] = red[0] * (1.0f / (float)P_POS);
}

extern "C" void kernel_launch(void* const* d_in, const int* in_sizes, int n_in,
                              void* d_out, int out_size, void* d_ws, size_t ws_size,
                              hipStream_t stream) {
    const float* feat    = (const float*)d_in[0];
    const int*   pos_idx = (const int*)d_in[1];
    const int*   neg_idx = (const int*)d_in[2];

    char* ws = (char*)d_ws;
    unsigned short* Sb = (unsigned short*)ws;                 // 32 MiB bf16 sigmoid
    float* xx    = (float*)(ws + 33554432);                   // 256 KiB row norms
    int*   hp    = (int*)  (ws + 33816576);                   // 160 KiB
    int*   hn    = (int*)  (ws + 33980416);                   // 160 KiB
    float* terms = (float*)(ws + 34144256);                   // 160 KiB

    sigmoid_norm_k<<<M_ROWS / 4, 256, 0, stream>>>(feat, Sb, xx);

    dim3 g2(P_POS / 64, 2, K_CLS);
    select_k<<<g2, 256, 0, stream>>>(Sb, xx, pos_idx, neg_idx, hp, hn);

    loss_k<<<(K_CLS * P_POS) / 4, 256, 0, stream>>>(Sb, pos_idx, neg_idx, hp, hn, terms);

    reduce_k<<<1, 1024, 0, stream>>>(terms, (float*)d_out);
}

// Round 2
// 284.941 us; speedup vs baseline: 1.4892x; 1.4892x over previous
//
#include <hip/hip_runtime.h>
#include <stdint.h>

#define M_ROWS 65536
#define C_DIM  256
#define K_CLS  20
#define P_POS  2048
#define MARGIN_F 0.3f
#define EPS_D (0.0001f / 256.0f)

typedef short  short8  __attribute__((ext_vector_type(8)));
typedef float  floatx4 __attribute__((ext_vector_type(4)));

__device__ __forceinline__ unsigned short f2bf(float x) {
    uint32_t u = __float_as_uint(x);
    u += 0x7fffu + ((u >> 16) & 1u);   // RNE
    return (unsigned short)(u >> 16);
}
__device__ __forceinline__ float bf2f(unsigned short h) {
    return __uint_as_float(((uint32_t)h) << 16);
}

// async 16B/lane global -> LDS (wave-uniform LDS base + lane*16)
__device__ __forceinline__ void async_copy16(const void* g, void* l) {
    __builtin_amdgcn_global_load_lds(
        (const __attribute__((address_space(1))) void*)g,
        (__attribute__((address_space(3))) void*)l, 16, 0, 0);
}

// ---------------- Kernel 1: sigmoid -> bf16 store + fp32 row norms ----------
__global__ __launch_bounds__(256) void sigmoid_norm_k(
        const float* __restrict__ feat,
        unsigned short* __restrict__ Sb,
        float* __restrict__ xx) {
    const int wave = threadIdx.x >> 6, lane = threadIdx.x & 63;
    const int row = blockIdx.x * 4 + wave;
    const float4 v = *(const float4*)(feat + (size_t)row * C_DIM + lane * 4);

    unsigned short b0 = f2bf(1.f / (1.f + __expf(-v.x)));
    unsigned short b1 = f2bf(1.f / (1.f + __expf(-v.y)));
    unsigned short b2 = f2bf(1.f / (1.f + __expf(-v.z)));
    unsigned short b3 = f2bf(1.f / (1.f + __expf(-v.w)));

    ushort4 st; st.x = b0; st.y = b1; st.z = b2; st.w = b3;
    *(ushort4*)(Sb + (size_t)row * C_DIM + lane * 4) = st;

    float s0 = bf2f(b0), s1 = bf2f(b1), s2 = bf2f(b2), s3 = bf2f(b3);
    float sum = s0 * s0 + s1 * s1 + s2 * s2 + s3 * s3;
#pragma unroll
    for (int off = 32; off; off >>= 1) sum += __shfl_down(sum, off);
    if (lane == 0) xx[row] = sum;
}

// ---------------- Kernel 2: fused distance-GEMM + arg-select ----------------
// Block tile 128i x 64j, 4 waves (2 i-halves x 2 j-halves), wave tile 64x32.
// A (128 rows x K=256) lives entirely in registers (gathered once, MFMA layout).
// B double-buffered in LDS (2 x 32 KB), staged via global_load_lds w/ XOR
// swizzle folded into the *global* source address (LDS dest must be
// lane-contiguous, so padding is impossible -> swizzle for bank evenness).
// Selection on g = yy_j - 2*(x_i . y_j): per-row-constant xx and the monotone
// clamp/sqrt/eps drop out of arg-select (clamp ties = duplicate rows, value-
// equivalent either way).
__global__ __launch_bounds__(256, 2) void select_k(
        const unsigned short* __restrict__ Sb,
        const float* __restrict__ xx,
        const int* __restrict__ pos_idx,
        const int* __restrict__ neg_idx,
        int* __restrict__ hp,
        int* __restrict__ hn) {
    __shared__ __align__(16) unsigned char Bt[2][64 * 512];   // 64 KiB total

    const int tid    = threadIdx.x;
    const int w      = tid >> 6;
    const int lane   = tid & 63;
    const int lane15 = lane & 15;
    const int quad   = lane >> 4;
    const int ih     = w >> 1;          // i-half: rows ih*64 .. +63
    const int jh     = (w & 1) * 32;    // j-offset within the 64-col B tile

    const int k      = blockIdx.z;
    const int isNeg  = blockIdx.y;
    const int i0     = blockIdx.x * 128;

    const int* __restrict__ idxA = pos_idx + k * P_POS;
    const int* __restrict__ idxB = (isNeg ? neg_idx : pos_idx) + k * P_POS;
    int*       outIdx            = (isNeg ? hn : hp) + k * P_POS;

    const char* SbB = (const char*)Sb;          // row stride 512 B

    // ---- staging-row indices for tile 0 (refilled one tile ahead) ----
    const int strow = (w << 4) + (lane >> 5);   // + it*2 per issue
    int g_st[8];
#pragma unroll
    for (int it = 0; it < 8; ++it) g_st[it] = idxB[strow + it * 2];

    // ---- A fragments: rows i0 + ih*64 + si*16 + lane15, full K in regs ----
    short8 A_reg[4][8];
#pragma unroll
    for (int si = 0; si < 4; ++si) {
        const int gi = idxA[i0 + ih * 64 + si * 16 + lane15];
        const char* rb = SbB + (size_t)gi * 512 + (quad << 4);
#pragma unroll
        for (int s = 0; s < 8; ++s)
            A_reg[si][s] = *(const short8*)(rb + s * 64);
    }

    // ---- stage tile 0 into Bt[0] ----
    {
        const int p = lane & 31;
#pragma unroll
        for (int it = 0; it < 8; ++it) {
            const int r  = strow + it * 2;           // 0..63 local B row
            const int gu = p ^ (r & 7);              // swizzled global 16B unit
            const char* ga = SbB + (size_t)g_st[it] * 512 + (gu << 4);
            char* la = (char*)(&Bt[0][0]) + (size_t)((w << 4) + it * 2) * 512;
            async_copy16(ga, la);
        }
    }
    // refill idx for tile 1
#pragma unroll
    for (int it = 0; it < 8; ++it) g_st[it] = idxB[64 + strow + it * 2];

    float bestv[16];
    int   bestj[16];
    const float binit = isNeg ? 3.4e38f : -3.4e38f;
#pragma unroll
    for (int t = 0; t < 16; ++t) { bestv[t] = binit; bestj[t] = 0; }

    for (int jc = 0; jc < 32; ++jc) {
        __syncthreads();   // prev compute done + this tile's loads drained

        // prefetch tile jc+1 into the other buffer (indices already resident)
        if (jc < 31) {
            const int p = lane & 31;
            char* lb = (char*)(&Bt[(jc + 1) & 1][0]);
#pragma unroll
            for (int it = 0; it < 8; ++it) {
                const int r  = strow + it * 2;
                const int gu = p ^ (r & 7);
                const char* ga = SbB + (size_t)g_st[it] * 512 + (gu << 4);
                async_copy16(ga, lb + (size_t)((w << 4) + it * 2) * 512);
            }
        }
        // refill idx for tile jc+2
        if (jc < 30) {
#pragma unroll
            for (int it = 0; it < 8; ++it)
                g_st[it] = idxB[(jc + 2) * 64 + strow + it * 2];
        }

        // yy for this tile's two column groups (used in epilogue)
        const int b0 = idxB[jc * 64 + jh + lane15];
        const int b1 = idxB[jc * 64 + jh + 16 + lane15];
        const float yv0 = xx[b0];
        const float yv1 = xx[b1];

        // ---- compute: 8 K-steps, A from regs, B from LDS (swizzled) ----
        const char* Bb = (const char*)(&Bt[jc & 1][0]);
        floatx4 acc[2][4];
#pragma unroll
        for (int ct = 0; ct < 2; ++ct)
#pragma unroll
            for (int si = 0; si < 4; ++si)
                acc[ct][si] = (floatx4){0.f, 0.f, 0.f, 0.f};

#pragma unroll
        for (int s = 0; s < 8; ++s) {
            short8 bf[2];
#pragma unroll
            for (int ct = 0; ct < 2; ++ct) {
                const int rB = jh + ct * 16 + lane15;
                const int p  = ((s << 2) + quad) ^ (lane15 & 7);
                bf[ct] = *(const short8*)(Bb + (size_t)rB * 512 + (p << 4));
            }
#pragma unroll
            for (int ct = 0; ct < 2; ++ct)
#pragma unroll
                for (int si = 0; si < 4; ++si)
                    acc[ct][si] = __builtin_amdgcn_mfma_f32_16x16x32_bf16(
                        A_reg[si][s], bf[ct], acc[ct][si], 0, 0, 0);
        }

        // ---- epilogue: g = yy - 2*dot; running arg-select (strict -> first j)
#pragma unroll
        for (int ct = 0; ct < 2; ++ct) {
            const float yv = ct ? yv1 : yv0;
            const int j = jc * 64 + jh + ct * 16 + lane15;
#pragma unroll
            for (int si = 0; si < 4; ++si)
#pragma unroll
                for (int r = 0; r < 4; ++r) {
                    const float g = fmaf(-2.f, acc[ct][si][r], yv);
                    const int slot = si * 4 + r;
                    const bool better = isNeg ? (g < bestv[slot]) : (g > bestv[slot]);
                    if (better) { bestv[slot] = g; bestj[slot] = j; }
                }
        }
    }

    // ---- cross-lane reduce over the 16 column-lanes (first-index ties) ----
#pragma unroll
    for (int slot = 0; slot < 16; ++slot) {
#pragma unroll
        for (int off = 1; off < 16; off <<= 1) {
            float ov = __shfl_xor(bestv[slot], off);
            int   oj = __shfl_xor(bestj[slot], off);
            bool better = isNeg
                ? (ov < bestv[slot] || (ov == bestv[slot] && oj < bestj[slot]))
                : (ov > bestv[slot] || (ov == bestv[slot] && oj < bestj[slot]));
            if (better) { bestv[slot] = ov; bestj[slot] = oj; }
        }
    }

    // ---- cross-wave combine (two j-halves per i-half) via LDS scratch ----
    __syncthreads();                      // everyone done with Bt reads
    float* sv = (float*)&Bt[0][0];        // [2 halves][128 rows]
    int*   sj = (int*)((char*)&Bt[0][0] + 1024);
    if (lane15 == 0) {
#pragma unroll
        for (int si = 0; si < 4; ++si)
#pragma unroll
            for (int r = 0; r < 4; ++r) {
                const int row  = ih * 64 + si * 16 + quad * 4 + r;
                const int half = w & 1;
                sv[half * 128 + row] = bestv[si * 4 + r];
                sj[half * 128 + row] = bestj[si * 4 + r];
            }
    }
    __syncthreads();
    if (tid < 128) {
        const float v0 = sv[tid], v1 = sv[128 + tid];
        const int   j0 = sj[tid], j1 = sj[128 + tid];
        const bool take1 = isNeg ? (v1 < v0 || (v1 == v0 && j1 < j0))
                                 : (v1 > v0 || (v1 == v0 && j1 < j0));
        outIdx[i0 + tid] = take1 ? j1 : j0;
    }
}

// ---------------- Kernel 3: per-anchor fp32 pdist + triplet term ------------
__global__ __launch_bounds__(256) void loss_k(
        const unsigned short* __restrict__ Sb,
        const int* __restrict__ pos_idx,
        const int* __restrict__ neg_idx,
        const int* __restrict__ hp,
        const int* __restrict__ hn,
        float* __restrict__ terms) {
    const int wave = threadIdx.x >> 6, lane = threadIdx.x & 63;
    const int a = blockIdx.x * 4 + wave;
    const int k = a >> 11;
    const int i = a & 2047;
    const int* pidx = pos_idx + (k << 11);
    const int* nidx = neg_idx + (k << 11);
    const int ga = pidx[i];
    const int gp = pidx[hp[a]];
    const int gn = nidx[hn[a]];

    const ushort4 va = *(const ushort4*)(Sb + (size_t)ga * C_DIM + lane * 4);
    const ushort4 vp = *(const ushort4*)(Sb + (size_t)gp * C_DIM + lane * 4);
    const ushort4 vn = *(const ushort4*)(Sb + (size_t)gn * C_DIM + lane * 4);

    float dp = 0.f, dn = 0.f;
    {
        float xa, d;
        xa = bf2f(va.x); d = xa - bf2f(vp.x); dp += d * d; d = xa - bf2f(vn.x); dn += d * d;
        xa = bf2f(va.y); d = xa - bf2f(vp.y); dp += d * d; d = xa - bf2f(vn.y); dn += d * d;
        xa = bf2f(va.z); d = xa - bf2f(vp.z); dp += d * d; d = xa - bf2f(vn.z); dn += d * d;
        xa = bf2f(va.w); d = xa - bf2f(vp.w); dp += d * d; d = xa - bf2f(vn.w); dn += d * d;
    }
#pragma unroll
    for (int off = 32; off; off >>= 1) {
        dp += __shfl_down(dp, off);
        dn += __shfl_down(dn, off);
    }
    if (lane == 0) {
        float d_p = sqrtf(fmaxf(dp, 0.f) + EPS_D);
        float d_n = sqrtf(fmaxf(dn, 0.f) + EPS_D);
        terms[a] = fmaxf(MARGIN_F + d_p - d_n, 0.f);
    }
}

// ---------------- Kernel 4: final reduction (sum of class means) ------------
__global__ __launch_bounds__(1024) void reduce_k(
        const float* __restrict__ terms, float* __restrict__ out) {
    __shared__ float red[1024];
    float s = 0.f;
    for (int i = threadIdx.x; i < K_CLS * P_POS; i += 1024) s += terms[i];
    red[threadIdx.x] = s;
    __syncthreads();
    for (int off = 512; off; off >>= 1) {
        if ((int)threadIdx.x < off) red[threadIdx.x] += red[threadIdx.x + off];
        __syncthreads();
    }
    if (threadIdx.x == 0) out[0] = red[0] * (1.0f / (float)P_POS);
}

extern "C" void kernel_launch(void* const* d_in, const int* in_sizes, int n_in,
                              void* d_out, int out_size, void* d_ws, size_t ws_size,
                              hipStream_t stream) {
    const float* feat    = (const float*)d_in[0];
    const int*   pos_idx = (const int*)d_in[1];
    const int*   neg_idx = (const int*)d_in[2];

    char* ws = (char*)d_ws;
    unsigned short* Sb = (unsigned short*)ws;                 // 32 MiB bf16 sigmoid
    float* xx    = (float*)(ws + 33554432);                   // 256 KiB row norms
    int*   hp    = (int*)  (ws + 33816576);                   // 160 KiB
    int*   hn    = (int*)  (ws + 33980416);                   // 160 KiB
    float* terms = (float*)(ws + 34144256);                   // 160 KiB

    sigmoid_norm_k<<<M_ROWS / 4, 256, 0, stream>>>(feat, Sb, xx);

    dim3 g2(P_POS / 128, 2, K_CLS);
    select_k<<<g2, 256, 0, stream>>>(Sb, xx, pos_idx, neg_idx, hp, hn);

    loss_k<<<(K_CLS * P_POS) / 4, 256, 0, stream>>>(Sb, pos_idx, neg_idx, hp, hn, terms);

    reduce_k<<<1, 1024, 0, stream>>>(terms, (float*)d_out);
}

// Round 3
// 278.662 us; speedup vs baseline: 1.5227x; 1.0225x over previous
//
#include <hip/hip_runtime.h>
#include <stdint.h>

#define M_ROWS 65536
#define C_DIM  256
#define K_CLS  20
#define P_POS  2048
#define MARGIN_F 0.3f
#define EPS_D (0.0001f / 256.0f)

typedef short  short8  __attribute__((ext_vector_type(8)));
typedef float  floatx4 __attribute__((ext_vector_type(4)));

__device__ __forceinline__ unsigned short f2bf(float x) {
    uint32_t u = __float_as_uint(x);
    u += 0x7fffu + ((u >> 16) & 1u);   // RNE
    return (unsigned short)(u >> 16);
}
__device__ __forceinline__ float bf2f(unsigned short h) {
    return __uint_as_float(((uint32_t)h) << 16);
}

// async 16B/lane global -> LDS (wave-uniform LDS base + lane*16)
__device__ __forceinline__ void async_copy16(const void* g, void* l) {
    __builtin_amdgcn_global_load_lds(
        (const __attribute__((address_space(1))) void*)g,
        (__attribute__((address_space(3))) void*)l, 16, 0, 0);
}

// ---------------- Kernel 1: sigmoid -> bf16 store + fp32 row norms ----------
__global__ __launch_bounds__(256) void sigmoid_norm_k(
        const float* __restrict__ feat,
        unsigned short* __restrict__ Sb,
        float* __restrict__ xx) {
    const int wave = threadIdx.x >> 6, lane = threadIdx.x & 63;
    const int row = blockIdx.x * 4 + wave;
    const float4 v = *(const float4*)(feat + (size_t)row * C_DIM + lane * 4);

    unsigned short b0 = f2bf(1.f / (1.f + __expf(-v.x)));
    unsigned short b1 = f2bf(1.f / (1.f + __expf(-v.y)));
    unsigned short b2 = f2bf(1.f / (1.f + __expf(-v.z)));
    unsigned short b3 = f2bf(1.f / (1.f + __expf(-v.w)));

    ushort4 st; st.x = b0; st.y = b1; st.z = b2; st.w = b3;
    *(ushort4*)(Sb + (size_t)row * C_DIM + lane * 4) = st;

    float s0 = bf2f(b0), s1 = bf2f(b1), s2 = bf2f(b2), s3 = bf2f(b3);
    float sum = s0 * s0 + s1 * s1 + s2 * s2 + s3 * s3;
#pragma unroll
    for (int off = 32; off; off >>= 1) sum += __shfl_down(sum, off);
    if (lane == 0) xx[row] = sum;
}

// ---------------- Kernel 2: fused distance-GEMM + arg-select ----------------
// Block tile 128i x 64j, 4 waves. A (128 x 256) in registers; B double-
// buffered in LDS via global_load_lds w/ XOR swizzle folded into the global
// source address. yy gathered ONCE per block into LDS (kills the in-loop
// dependent gather). Grid is linear: bid = i_blk*40 + ctid so all 16
// i-blocks of one (class,type) share bid%8 -> same XCD -> B-set (~1MB)
// goes L2-resident. Selection key g = yy - 2*x.y (xx/clamp/sqrt monotone-
// invariant for arg-select).
__global__ __launch_bounds__(256, 2) void select_k(
        const unsigned short* __restrict__ Sb,
        const float* __restrict__ xx,
        const int* __restrict__ pos_idx,
        const int* __restrict__ neg_idx,
        int* __restrict__ hp,
        int* __restrict__ hn) {
    __shared__ __align__(16) unsigned char Bt[2][64 * 512];   // 64 KiB
    __shared__ float yyL[P_POS];                              // 8 KiB

    const int tid    = threadIdx.x;
    const int w      = tid >> 6;
    const int lane   = tid & 63;
    const int lane15 = lane & 15;
    const int quad   = lane >> 4;
    const int ih     = w >> 1;          // i-half: rows ih*64 .. +63
    const int jh     = (w & 1) * 32;    // j-offset within the 64-col B tile

    const int bid    = blockIdx.x;      // 640 = 16 i-blocks x 40 (k,type)
    const int ctid   = bid % 40;        // same ctid -> same XCD (mod-8)
    const int i_blk  = bid / 40;
    const int k      = ctid >> 1;
    const int isNeg  = ctid & 1;
    const int i0     = i_blk * 128;

    const int* __restrict__ idxA = pos_idx + k * P_POS;
    const int* __restrict__ idxB = (isNeg ? neg_idx : pos_idx) + k * P_POS;
    int*       outIdx            = (isNeg ? hn : hp) + k * P_POS;

    const char* SbB = (const char*)Sb;          // row stride 512 B

    // ---- precomputed per-lane staging offsets (hoisted swizzle math) ----
    const int strow = (w << 4) + (lane >> 5);
    int goff[8];
#pragma unroll
    for (int it = 0; it < 8; ++it)
        goff[it] = ((lane & 31) ^ ((it * 2 + (lane >> 5)) & 7)) << 4;

    // ---- stage tile 0 ASAP (overlaps yy fill + A gather) ----
    int g_st[8];
#pragma unroll
    for (int it = 0; it < 8; ++it) g_st[it] = idxB[strow + it * 2];
#pragma unroll
    for (int it = 0; it < 8; ++it) {
        const char* ga = SbB + ((size_t)(uint32_t)g_st[it] << 9) + goff[it];
        async_copy16(ga, (char*)&Bt[0][0] + ((w << 4) + it * 2) * 512);
    }

    // ---- yy for the whole 2048-j set, once per block, into LDS ----
    for (int t = tid; t < P_POS; t += 256) yyL[t] = xx[idxB[t]];

    // ---- A fragments: rows i0 + ih*64 + si*16 + lane15, full K in regs ----
    short8 A_reg[4][8];
#pragma unroll
    for (int si = 0; si < 4; ++si) {
        const int gi = idxA[i0 + ih * 64 + si * 16 + lane15];
        const char* rb = SbB + (size_t)gi * 512 + (quad << 4);
#pragma unroll
        for (int s = 0; s < 8; ++s)
            A_reg[si][s] = *(const short8*)(rb + s * 64);
    }

    // refill idx for tile 1
#pragma unroll
    for (int it = 0; it < 8; ++it) g_st[it] = idxB[64 + strow + it * 2];

    // ---- precomputed LDS read offsets (within a buffer) ----
    int boff[2][8];
#pragma unroll
    for (int ct = 0; ct < 2; ++ct)
#pragma unroll
        for (int s = 0; s < 8; ++s)
            boff[ct][s] = (jh + ct * 16 + lane15) * 512 +
                          ((((s << 2) + quad) ^ (lane15 & 7)) << 4);

    float bestv[16];
    int   bestj[16];
    const float binit = isNeg ? 3.4e38f : -3.4e38f;
#pragma unroll
    for (int t = 0; t < 16; ++t) { bestv[t] = binit; bestj[t] = 0; }

#pragma unroll 2
    for (int jc = 0; jc < 32; ++jc) {
        __syncthreads();   // prev readers done + this tile's loads drained

        // yv for this tile (LDS broadcast reads; latency hidden under MFMA)
        const float yv0 = yyL[jc * 64 + jh + lane15];
        const float yv1 = yyL[jc * 64 + jh + 16 + lane15];

        // prefetch tile jc+1 into the other buffer
        if (jc < 31) {
            char* lb = (char*)(&Bt[(jc + 1) & 1][0]);
#pragma unroll
            for (int it = 0; it < 8; ++it) {
                const char* ga = SbB + ((size_t)(uint32_t)g_st[it] << 9) + goff[it];
                async_copy16(ga, lb + ((w << 4) + it * 2) * 512);
            }
        }
        // refill idx for tile jc+2
        if (jc < 30) {
#pragma unroll
            for (int it = 0; it < 8; ++it)
                g_st[it] = idxB[(jc + 2) * 64 + strow + it * 2];
        }

        // ---- compute: 8 K-steps, A from regs, B from LDS ----
        const char* Bb = (const char*)(&Bt[jc & 1][0]);
        floatx4 acc[2][4];
#pragma unroll
        for (int ct = 0; ct < 2; ++ct)
#pragma unroll
            for (int si = 0; si < 4; ++si)
                acc[ct][si] = (floatx4){0.f, 0.f, 0.f, 0.f};

#pragma unroll
        for (int s = 0; s < 8; ++s) {
            short8 bf0 = *(const short8*)(Bb + boff[0][s]);
            short8 bf1 = *(const short8*)(Bb + boff[1][s]);
#pragma unroll
            for (int si = 0; si < 4; ++si)
                acc[0][si] = __builtin_amdgcn_mfma_f32_16x16x32_bf16(
                    A_reg[si][s], bf0, acc[0][si], 0, 0, 0);
#pragma unroll
            for (int si = 0; si < 4; ++si)
                acc[1][si] = __builtin_amdgcn_mfma_f32_16x16x32_bf16(
                    A_reg[si][s], bf1, acc[1][si], 0, 0, 0);
        }

        // ---- epilogue: g = yy - 2*dot; strict update -> first-j ties ----
#pragma unroll
        for (int ct = 0; ct < 2; ++ct) {
            const float yv = ct ? yv1 : yv0;
            const int j = jc * 64 + jh + ct * 16 + lane15;
#pragma unroll
            for (int si = 0; si < 4; ++si)
#pragma unroll
                for (int r = 0; r < 4; ++r) {
                    const float g = fmaf(-2.f, acc[ct][si][r], yv);
                    const int slot = si * 4 + r;
                    const bool better = isNeg ? (g < bestv[slot]) : (g > bestv[slot]);
                    if (better) { bestv[slot] = g; bestj[slot] = j; }
                }
        }
    }

    // ---- cross-lane reduce over the 16 column-lanes (first-index ties) ----
#pragma unroll
    for (int slot = 0; slot < 16; ++slot) {
#pragma unroll
        for (int off = 1; off < 16; off <<= 1) {
            float ov = __shfl_xor(bestv[slot], off);
            int   oj = __shfl_xor(bestj[slot], off);
            bool better = isNeg
                ? (ov < bestv[slot] || (ov == bestv[slot] && oj < bestj[slot]))
                : (ov > bestv[slot] || (ov == bestv[slot] && oj < bestj[slot]));
            if (better) { bestv[slot] = ov; bestj[slot] = oj; }
        }
    }

    // ---- cross-wave combine (two j-halves per i-half) via LDS scratch ----
    __syncthreads();                      // everyone done with Bt reads
    float* sv = (float*)&Bt[0][0];        // [2 halves][128 rows]
    int*   sj = (int*)((char*)&Bt[0][0] + 1024);
    if (lane15 == 0) {
#pragma unroll
        for (int si = 0; si < 4; ++si)
#pragma unroll
            for (int r = 0; r < 4; ++r) {
                const int row  = ih * 64 + si * 16 + quad * 4 + r;
                const int half = w & 1;
                sv[half * 128 + row] = bestv[si * 4 + r];
                sj[half * 128 + row] = bestj[si * 4 + r];
            }
    }
    __syncthreads();
    if (tid < 128) {
        const float v0 = sv[tid], v1 = sv[128 + tid];
        const int   j0 = sj[tid], j1 = sj[128 + tid];
        const bool take1 = isNeg ? (v1 < v0 || (v1 == v0 && j1 < j0))
                                 : (v1 > v0 || (v1 == v0 && j1 < j0));
        outIdx[i0 + tid] = take1 ? j1 : j0;
    }
}

// ---------------- Kernel 3: per-anchor fp32 pdist + triplet term ------------
__global__ __launch_bounds__(256) void loss_k(
        const unsigned short* __restrict__ Sb,
        const int* __restrict__ pos_idx,
        const int* __restrict__ neg_idx,
        const int* __restrict__ hp,
        const int* __restrict__ hn,
        float* __restrict__ terms) {
    const int wave = threadIdx.x >> 6, lane = threadIdx.x & 63;
    const int a = blockIdx.x * 4 + wave;
    const int k = a >> 11;
    const int i = a & 2047;
    const int* pidx = pos_idx + (k << 11);
    const int* nidx = neg_idx + (k << 11);
    const int ga = pidx[i];
    const int gp = pidx[hp[a]];
    const int gn = nidx[hn[a]];

    const ushort4 va = *(const ushort4*)(Sb + (size_t)ga * C_DIM + lane * 4);
    const ushort4 vp = *(const ushort4*)(Sb + (size_t)gp * C_DIM + lane * 4);
    const ushort4 vn = *(const ushort4*)(Sb + (size_t)gn * C_DIM + lane * 4);

    float dp = 0.f, dn = 0.f;
    {
        float xa, d;
        xa = bf2f(va.x); d = xa - bf2f(vp.x); dp += d * d; d = xa - bf2f(vn.x); dn += d * d;
        xa = bf2f(va.y); d = xa - bf2f(vp.y); dp += d * d; d = xa - bf2f(vn.y); dn += d * d;
        xa = bf2f(va.z); d = xa - bf2f(vp.z); dp += d * d; d = xa - bf2f(vn.z); dn += d * d;
        xa = bf2f(va.w); d = xa - bf2f(vp.w); dp += d * d; d = xa - bf2f(vn.w); dn += d * d;
    }
#pragma unroll
    for (int off = 32; off; off >>= 1) {
        dp += __shfl_down(dp, off);
        dn += __shfl_down(dn, off);
    }
    if (lane == 0) {
        float d_p = sqrtf(fmaxf(dp, 0.f) + EPS_D);
        float d_n = sqrtf(fmaxf(dn, 0.f) + EPS_D);
        terms[a] = fmaxf(MARGIN_F + d_p - d_n, 0.f);
    }
}

// ---------------- Kernel 4: final reduction (sum of class means) ------------
__global__ __launch_bounds__(1024) void reduce_k(
        const float* __restrict__ terms, float* __restrict__ out) {
    __shared__ float red[1024];
    float s = 0.f;
    for (int i = threadIdx.x; i < K_CLS * P_POS; i += 1024) s += terms[i];
    red[threadIdx.x] = s;
    __syncthreads();
    for (int off = 512; off; off >>= 1) {
        if ((int)threadIdx.x < off) red[threadIdx.x] += red[threadIdx.x + off];
        __syncthreads();
    }
    if (threadIdx.x == 0) out[0] = red[0] * (1.0f / (float)P_POS);
}

extern "C" void kernel_launch(void* const* d_in, const int* in_sizes, int n_in,
                              void* d_out, int out_size, void* d_ws, size_t ws_size,
                              hipStream_t stream) {
    const float* feat    = (const float*)d_in[0];
    const int*   pos_idx = (const int*)d_in[1];
    const int*   neg_idx = (const int*)d_in[2];

    char* ws = (char*)d_ws;
    unsigned short* Sb = (unsigned short*)ws;                 // 32 MiB bf16 sigmoid
    float* xx    = (float*)(ws + 33554432);                   // 256 KiB row norms
    int*   hp    = (int*)  (ws + 33816576);                   // 160 KiB
    int*   hn    = (int*)  (ws + 33980416);                   // 160 KiB
    float* terms = (float*)(ws + 34144256);                   // 80 KiB

    sigmoid_norm_k<<<M_ROWS / 4, 256, 0, stream>>>(feat, Sb, xx);

    select_k<<<16 * 40, 256, 0, stream>>>(Sb, xx, pos_idx, neg_idx, hp, hn);

    loss_k<<<(K_CLS * P_POS) / 4, 256, 0, stream>>>(Sb, pos_idx, neg_idx, hp, hn, terms);

    reduce_k<<<1, 1024, 0, stream>>>(terms, (float*)d_out);
}

// Round 5
// 240.036 us; speedup vs baseline: 1.7677x; 1.1609x over previous
//
#include <hip/hip_runtime.h>
#include <stdint.h>

#define M_ROWS 65536
#define C_DIM  256
#define K_CLS  20
#define P_POS  2048
#define MARGIN_F 0.3f
#define EPS_D (0.0001f / 256.0f)

typedef short  short8  __attribute__((ext_vector_type(8)));
typedef float  floatx4 __attribute__((ext_vector_type(4)));

__device__ __forceinline__ unsigned short f2bf(float x) {
    uint32_t u = __float_as_uint(x);
    u += 0x7fffu + ((u >> 16) & 1u);   // RNE
    return (unsigned short)(u >> 16);
}
__device__ __forceinline__ float bf2f(unsigned short h) {
    return __uint_as_float(((uint32_t)h) << 16);
}

// async 16B/lane global -> LDS (wave-uniform LDS base + lane*16)
__device__ __forceinline__ void async_copy16(const void* g, void* l) {
    __builtin_amdgcn_global_load_lds(
        (const __attribute__((address_space(1))) void*)g,
        (__attribute__((address_space(3))) void*)l, 16, 0, 0);
}

// ---------------- Kernel 1: sigmoid -> bf16 store + fp32 row norms ----------
__global__ __launch_bounds__(256) void sigmoid_norm_k(
        const float* __restrict__ feat,
        unsigned short* __restrict__ Sb,
        float* __restrict__ xx) {
    const int wave = threadIdx.x >> 6, lane = threadIdx.x & 63;
    const int row = blockIdx.x * 4 + wave;
    const float4 v = *(const float4*)(feat + (size_t)row * C_DIM + lane * 4);

    unsigned short b0 = f2bf(1.f / (1.f + __expf(-v.x)));
    unsigned short b1 = f2bf(1.f / (1.f + __expf(-v.y)));
    unsigned short b2 = f2bf(1.f / (1.f + __expf(-v.z)));
    unsigned short b3 = f2bf(1.f / (1.f + __expf(-v.w)));

    ushort4 st; st.x = b0; st.y = b1; st.z = b2; st.w = b3;
    *(ushort4*)(Sb + (size_t)row * C_DIM + lane * 4) = st;

    float s0 = bf2f(b0), s1 = bf2f(b1), s2 = bf2f(b2), s3 = bf2f(b3);
    float sum = s0 * s0 + s1 * s1 + s2 * s2 + s3 * s3;
#pragma unroll
    for (int off = 32; off; off >>= 1) sum += __shfl_down(sum, off);
    if (lane == 0) xx[row] = sum;
}

// ---------------- Kernel 2: fused distance-GEMM + arg-select ----------------
// Block 128i x 32j, 4 waves stacked in i (wave tile 32x32). A (32 x 256) in
// 64 VGPRs/wave; B double-buffered 2 x 16 KB (LDS 32 KB) via global_load_lds
// with XOR swizzle folded into the global source address. yy pipelined in
// registers. Arg-select key: enc = (bits(yy - 2*x.y) & ~2047) | j  -- low 11
// mantissa bits CLEARED then replaced by j (v_and_or_b32); single v_max/v_min
// tracks value+index. Flips confined to the 2^-12-rel quantization bucket.
// Grid 640 = 16 i-blk x 40 (k,type); bid%8 = ctid%8 -> B-set L2-resident.
// 3 blocks/CU -> 768 >= 640 fully co-resident, no tail.
__global__ __launch_bounds__(256, 3) void select_k(
        const unsigned short* __restrict__ Sb,
        const float* __restrict__ xx,
        const int* __restrict__ pos_idx,
        const int* __restrict__ neg_idx,
        int* __restrict__ hp,
        int* __restrict__ hn) {
    __shared__ __align__(16) unsigned char Bt[2][32 * 512];   // 32 KiB

    const int tid    = threadIdx.x;
    const int w      = tid >> 6;
    const int lane   = tid & 63;
    const int lane15 = lane & 15;
    const int quad   = lane >> 4;
    const int hi5    = lane >> 5;       // staging sub-row

    const int bid    = blockIdx.x;      // 640 = 16 i-blocks x 40 (k,type)
    const int ctid   = bid % 40;        // same ctid -> same XCD (mod-8)
    const int i_blk  = bid / 40;
    const int k      = ctid >> 1;
    const int isNeg  = ctid & 1;
    const int i0     = i_blk * 128;

    const int* __restrict__ idxA = pos_idx + k * P_POS;
    const int* __restrict__ idxB = (isNeg ? neg_idx : pos_idx) + k * P_POS;
    int*       outIdx            = (isNeg ? hn : hp) + k * P_POS;

    const char* SbB = (const char*)Sb;          // row stride 512 B

    // ---- per-lane staging offsets (swizzled global 16B-unit) ----
    int goff[4];
#pragma unroll
    for (int c = 0; c < 4; ++c)
        goff[c] = ((lane & 31) ^ ((c * 2 + hi5) & 7)) << 4;
    const int strow = w * 8 + hi5;      // + c*2 per copy

    // ---- stage tile 0 into Bt[0] ----
    int g_st[4];
#pragma unroll
    for (int c = 0; c < 4; ++c) g_st[c] = idxB[strow + c * 2];
#pragma unroll
    for (int c = 0; c < 4; ++c)
        async_copy16(SbB + ((size_t)(uint32_t)g_st[c] << 9) + goff[c],
                     (char*)&Bt[0][0] + (w * 8 + c * 2) * 512);
    // refill for tile 1
#pragma unroll
    for (int c = 0; c < 4; ++c) g_st[c] = idxB[32 + strow + c * 2];

    // ---- yv warmup: tile-0 values (dependent chain, once) + tile-1 idx ----
    float yv0 = xx[idxB[lane15]];
    float yv1 = xx[idxB[16 + lane15]];
    int idx_n0 = idxB[32 + lane15];
    int idx_n1 = idxB[48 + lane15];

    // ---- A fragments: rows i0 + w*32 + si*16 + lane15, full K in regs ----
    short8 A_reg[2][8];
#pragma unroll
    for (int si = 0; si < 2; ++si) {
        const int gi = idxA[i0 + w * 32 + si * 16 + lane15];
        const char* rb = SbB + (size_t)gi * 512 + (quad << 4);
#pragma unroll
        for (int s = 0; s < 8; ++s)
            A_reg[si][s] = *(const short8*)(rb + s * 64);
    }

    // ---- LDS read offsets within a buffer ----
    int boff[8];
#pragma unroll
    for (int s = 0; s < 8; ++s)
        boff[s] = lane15 * 512 + ((((s << 2) + quad) ^ (lane15 & 7)) << 4);

    float bestv[16];
    const float binit = isNeg ? 3.4e38f : -3.4e38f;
#pragma unroll
    for (int t = 0; t < 16; ++t) bestv[t] = binit;

#pragma unroll 2
    for (int jc = 0; jc < 64; ++jc) {
        __syncthreads();   // prev readers done + this tile's loads drained

        // xx prefetch for tile jc+1 (idx loaded last iter)
        const float nv0 = xx[idx_n0];
        const float nv1 = xx[idx_n1];

        // stage tile jc+1 into the other buffer
        if (jc < 63) {
            char* lb = (char*)(&Bt[(jc + 1) & 1][0]);
#pragma unroll
            for (int c = 0; c < 4; ++c)
                async_copy16(SbB + ((size_t)(uint32_t)g_st[c] << 9) + goff[c],
                             lb + (w * 8 + c * 2) * 512);
        }
        // refills for tile jc+2 (clamped; dead on last iters)
        {
            const int nt = (jc < 62 ? jc + 2 : 63) * 32;
#pragma unroll
            for (int c = 0; c < 4; ++c) g_st[c] = idxB[nt + strow + c * 2];
            idx_n0 = idxB[nt + lane15];
            idx_n1 = idxB[nt + 16 + lane15];
        }

        // ---- compute: 8 K-steps, A from regs, B from LDS ----
        const char* Bb = (const char*)(&Bt[jc & 1][0]);
        floatx4 acc[2][2];
#pragma unroll
        for (int ct = 0; ct < 2; ++ct)
#pragma unroll
            for (int si = 0; si < 2; ++si)
                acc[ct][si] = (floatx4){0.f, 0.f, 0.f, 0.f};

#pragma unroll
        for (int s = 0; s < 8; ++s) {
            short8 bf0 = *(const short8*)(Bb + boff[s]);
            short8 bf1 = *(const short8*)(Bb + boff[s] + 8192);
            acc[0][0] = __builtin_amdgcn_mfma_f32_16x16x32_bf16(A_reg[0][s], bf0, acc[0][0], 0, 0, 0);
            acc[0][1] = __builtin_amdgcn_mfma_f32_16x16x32_bf16(A_reg[1][s], bf0, acc[0][1], 0, 0, 0);
            acc[1][0] = __builtin_amdgcn_mfma_f32_16x16x32_bf16(A_reg[0][s], bf1, acc[1][0], 0, 0, 0);
            acc[1][1] = __builtin_amdgcn_mfma_f32_16x16x32_bf16(A_reg[1][s], bf1, acc[1][1], 0, 0, 0);
        }

        // ---- epilogue: enc = (bits(g) & ~2047) | j; single max/min ----
        const uint32_t jb0 = (uint32_t)((jc << 5) | lane15);
        const uint32_t jb1 = jb0 | 16u;
#pragma unroll
        for (int ct = 0; ct < 2; ++ct) {
            const float yv = ct ? yv1 : yv0;
            const uint32_t jb = ct ? jb1 : jb0;
#pragma unroll
            for (int si = 0; si < 2; ++si)
#pragma unroll
                for (int r = 0; r < 4; ++r) {
                    const float g = fmaf(-2.f, acc[ct][si][r], yv);
                    const float enc = __uint_as_float(
                        (__float_as_uint(g) & 0xFFFFF800u) | jb);  // v_and_or_b32
                    const int slot = ct * 8 + si * 4 + r;
                    bestv[slot] = isNeg ? fminf(bestv[slot], enc)
                                        : fmaxf(bestv[slot], enc);
                }
        }
        yv0 = nv0; yv1 = nv1;
    }

    // ---- reduce over the 16 column-lanes (index rides in the bits) ----
#pragma unroll
    for (int slot = 0; slot < 16; ++slot) {
#pragma unroll
        for (int off = 1; off < 16; off <<= 1) {
            const float ov = __shfl_xor(bestv[slot], off);
            bestv[slot] = isNeg ? fminf(bestv[slot], ov) : fmaxf(bestv[slot], ov);
        }
    }
    if (lane15 == 0) {
#pragma unroll
        for (int si = 0; si < 2; ++si)
#pragma unroll
            for (int r = 0; r < 4; ++r) {
                const float e0 = bestv[si * 4 + r];
                const float e1 = bestv[8 + si * 4 + r];
                const float e = isNeg ? fminf(e0, e1) : fmaxf(e0, e1);
                const int row = w * 32 + si * 16 + quad * 4 + r;
                outIdx[i0 + row] = (int)(__float_as_uint(e) & 2047u);
            }
    }
}

// ---------------- Kernel 3: per-anchor fp32 pdist + triplet term ------------
__global__ __launch_bounds__(256) void loss_k(
        const unsigned short* __restrict__ Sb,
        const int* __restrict__ pos_idx,
        const int* __restrict__ neg_idx,
        const int* __restrict__ hp,
        const int* __restrict__ hn,
        float* __restrict__ terms) {
    const int wave = threadIdx.x >> 6, lane = threadIdx.x & 63;
    const int a = blockIdx.x * 4 + wave;
    const int k = a >> 11;
    const int i = a & 2047;
    const int* pidx = pos_idx + (k << 11);
    const int* nidx = neg_idx + (k << 11);
    const int ga = pidx[i];
    const int gp = pidx[hp[a]];
    const int gn = nidx[hn[a]];

    const ushort4 va = *(const ushort4*)(Sb + (size_t)ga * C_DIM + lane * 4);
    const ushort4 vp = *(const ushort4*)(Sb + (size_t)gp * C_DIM + lane * 4);
    const ushort4 vn = *(const ushort4*)(Sb + (size_t)gn * C_DIM + lane * 4);

    float dp = 0.f, dn = 0.f;
    {
        float xa, d;
        xa = bf2f(va.x); d = xa - bf2f(vp.x); dp += d * d; d = xa - bf2f(vn.x); dn += d * d;
        xa = bf2f(va.y); d = xa - bf2f(vp.y); dp += d * d; d = xa - bf2f(vn.y); dn += d * d;
        xa = bf2f(va.z); d = xa - bf2f(vp.z); dp += d * d; d = xa - bf2f(vn.z); dn += d * d;
        xa = bf2f(va.w); d = xa - bf2f(vp.w); dp += d * d; d = xa - bf2f(vn.w); dn += d * d;
    }
#pragma unroll
    for (int off = 32; off; off >>= 1) {
        dp += __shfl_down(dp, off);
        dn += __shfl_down(dn, off);
    }
    if (lane == 0) {
        float d_p = sqrtf(fmaxf(dp, 0.f) + EPS_D);
        float d_n = sqrtf(fmaxf(dn, 0.f) + EPS_D);
        terms[a] = fmaxf(MARGIN_F + d_p - d_n, 0.f);
    }
}

// ---------------- Kernel 4: final reduction (sum of class means) ------------
__global__ __launch_bounds__(1024) void reduce_k(
        const float* __restrict__ terms, float* __restrict__ out) {
    __shared__ float red[1024];
    float s = 0.f;
    for (int i = threadIdx.x; i < K_CLS * P_POS; i += 1024) s += terms[i];
    red[threadIdx.x] = s;
    __syncthreads();
    for (int off = 512; off; off >>= 1) {
        if ((int)threadIdx.x < off) red[threadIdx.x] += red[threadIdx.x + off];
        __syncthreads();
    }
    if (threadIdx.x == 0) out[0] = red[0] * (1.0f / (float)P_POS);
}

extern "C" void kernel_launch(void* const* d_in, const int* in_sizes, int n_in,
                              void* d_out, int out_size, void* d_ws, size_t ws_size,
                              hipStream_t stream) {
    const float* feat    = (const float*)d_in[0];
    const int*   pos_idx = (const int*)d_in[1];
    const int*   neg_idx = (const int*)d_in[2];

    char* ws = (char*)d_ws;
    unsigned short* Sb = (unsigned short*)ws;                 // 32 MiB bf16 sigmoid
    float* xx    = (float*)(ws + 33554432);                   // 256 KiB row norms
    int*   hp    = (int*)  (ws + 33816576);                   // 160 KiB
    int*   hn    = (int*)  (ws + 33980416);                   // 160 KiB
    float* terms = (float*)(ws + 34144256);                   // 80 KiB

    sigmoid_norm_k<<<M_ROWS / 4, 256, 0, stream>>>(feat, Sb, xx);

    select_k<<<16 * 40, 256, 0, stream>>>(Sb, xx, pos_idx, neg_idx, hp, hn);

    loss_k<<<(K_CLS * P_POS) / 4, 256, 0, stream>>>(Sb, pos_idx, neg_idx, hp, hn, terms);

    reduce_k<<<1, 1024, 0, stream>>>(terms, (float*)d_out);
}